// Round 2
// baseline (1595.973 us; speedup 1.0000x reference)
//
#include <hip/hip_runtime.h>
#include <hip/hip_bf16.h>

#define T_TOK 4096
#define HID   2048
#define FFN   7168
#define NEXP  8
#define BM    128
#define BN    128
#define BK    64
#define MAXTILES 72
#define NPAIR (T_TOK * 2)

typedef __attribute__((ext_vector_type(8))) short bf16x8;
typedef __attribute__((ext_vector_type(4))) short bf16x4;
typedef __attribute__((ext_vector_type(4))) float f32x4;

__device__ __forceinline__ short f2bf(float f) {
    union { __hip_bfloat16 h; short s; } u;
    u.h = __float2bfloat16(f);
    return u.s;
}

// ---------------- Router: logits -> softmax -> top2 -> renorm ----------------
__global__ __launch_bounds__(256) void moe_router(
    const float* __restrict__ x, const float* __restrict__ gw,
    int* __restrict__ counts, int* __restrict__ sel0, int* __restrict__ sel1,
    float* __restrict__ w0o, float* __restrict__ w1o)
{
    int wave = threadIdx.x >> 6, lane = threadIdx.x & 63;
    int t = blockIdx.x * 4 + wave;
    const float* xr = x + (size_t)t * HID;
    float acc[NEXP];
#pragma unroll
    for (int e = 0; e < NEXP; ++e) acc[e] = 0.f;
    for (int i = 0; i < HID / 64; ++i) {
        int k = lane + i * 64;
        float xv = xr[k];
        const float4* g = reinterpret_cast<const float4*>(gw + (size_t)k * NEXP);
        float4 g0 = g[0], g1 = g[1];
        acc[0] += xv * g0.x; acc[1] += xv * g0.y; acc[2] += xv * g0.z; acc[3] += xv * g0.w;
        acc[4] += xv * g1.x; acc[5] += xv * g1.y; acc[6] += xv * g1.z; acc[7] += xv * g1.w;
    }
#pragma unroll
    for (int e = 0; e < NEXP; ++e) {
        float v = acc[e];
#pragma unroll
        for (int s = 32; s > 0; s >>= 1) v += __shfl_xor(v, s);
        acc[e] = v;
    }
    if (lane == 0) {
        float mx = acc[0];
        for (int e = 1; e < NEXP; ++e) mx = fmaxf(mx, acc[e]);
        float p[NEXP];
        for (int e = 0; e < NEXP; ++e) p[e] = __expf(acc[e] - mx);
        // top-2 with lowest-index tie-break (strict >), renorm cancels denom
        int e0 = 0;
        for (int e = 1; e < NEXP; ++e) if (p[e] > p[e0]) e0 = e;
        int e1 = (e0 == 0) ? 1 : 0;
        for (int e = 0; e < NEXP; ++e) if (e != e0 && p[e] > p[e1]) e1 = e;
        float rs = p[e0] + p[e1];
        sel0[t] = e0; sel1[t] = e1;
        w0o[t] = p[e0] / rs; w1o[t] = p[e1] / rs;
        atomicAdd(&counts[e0], 1); atomicAdd(&counts[e1], 1);
    }
}

// ---------------- Tile planner (1 thread; trivial) ----------------
__global__ void moe_tiles(const int* __restrict__ counts, int* __restrict__ bases,
                          int* __restrict__ tileE, int* __restrict__ tileM,
                          int* __restrict__ numTiles)
{
    if (threadIdx.x == 0 && blockIdx.x == 0) {
        int b = 0, nt = 0;
        for (int e = 0; e < NEXP; ++e) {
            bases[e] = b;
            int c = counts[e];
            for (int m = 0; m * BM < c; ++m) { tileE[nt] = e; tileM[nt] = m; ++nt; }
            b += c;
        }
        *numTiles = nt;
    }
}

// ---------------- Deterministic scatter: block e scans tokens in order ----------------
__global__ __launch_bounds__(256) void moe_scatter(
    const int* __restrict__ sel0, const int* __restrict__ sel1,
    const float* __restrict__ w0, const float* __restrict__ w1,
    const int* __restrict__ bases, int* __restrict__ pairTok, float* __restrict__ pairW)
{
    int e = blockIdx.x;
    __shared__ int wsum[4];
    __shared__ int runningS;
    int tid = threadIdx.x, wave = tid >> 6, lane = tid & 63;
    if (tid == 0) runningS = bases[e];
    __syncthreads();
    for (int i0 = 0; i0 < T_TOK; i0 += 256) {
        int t = i0 + tid;
        bool f0 = (sel0[t] == e), f1 = (sel1[t] == e);
        bool sel = f0 || f1;
        unsigned long long m = __ballot(sel);
        if (lane == 0) wsum[wave] = __popcll(m);
        __syncthreads();
        int woff = 0;
#pragma unroll
        for (int w = 0; w < 4; ++w) if (w < wave) woff += wsum[w];
        int tot = wsum[0] + wsum[1] + wsum[2] + wsum[3];
        int pre = __popcll(m & ((1ull << lane) - 1ull));
        if (sel) {
            int pos = runningS + woff + pre;
            pairTok[pos] = t;
            pairW[pos] = f0 ? w0[t] : w1[t];
        }
        __syncthreads();
        if (tid == 0) runningS += tot;
        __syncthreads();
    }
}

// ---------------- GEMM1: h = silu(x@W1) * (x@W3), grouped by expert ----------------
__global__ __launch_bounds__(256, 2) void moe_g1(
    const float* __restrict__ x, const float* __restrict__ w1s, const float* __restrict__ w3s,
    const int* __restrict__ counts, const int* __restrict__ bases,
    const int* __restrict__ numTiles, const int* __restrict__ tileE, const int* __restrict__ tileM,
    const int* __restrict__ pairTok, __hip_bfloat16* __restrict__ hbuf,
    int chunkF0, int Fc)
{
    int ti = blockIdx.y;
    if (ti >= *numTiles) return;
    int e = tileE[ti], m0 = tileM[ti] * BM;
    int base = bases[e], cnt = counts[e];
    int rows = cnt - m0; if (rows > BM) rows = BM;
    int n0 = blockIdx.x * BN;        // within chunk (h col)
    int gn0 = chunkF0 + n0;          // global FFN col

    __shared__ __align__(16) short As[BM * BK];
    __shared__ __align__(16) short B1s[BN * BK];
    __shared__ __align__(16) short B3s[BN * BK];
    __shared__ int tokS[BM];

    int tid = threadIdx.x;
    if (tid < BM) tokS[tid] = (tid < rows) ? pairTok[base + m0 + tid] : 0;
    __syncthreads();

    int wave = tid >> 6, lane = tid & 63;
    int wm = (wave >> 1) * 64, wn = (wave & 1) * 64;

    f32x4 acc1[4][4], acc3[4][4];
#pragma unroll
    for (int i = 0; i < 4; ++i)
#pragma unroll
        for (int j = 0; j < 4; ++j) { acc1[i][j] = (f32x4){0.f,0.f,0.f,0.f}; acc3[i][j] = (f32x4){0.f,0.f,0.f,0.f}; }

    const float* W1 = w1s + (size_t)e * HID * FFN;
    const float* W3 = w3s + (size_t)e * HID * FFN;
    int rb = tid >> 3, kbo = (tid & 7) * 8;

#pragma unroll 1
    for (int k0 = 0; k0 < HID; k0 += BK) {
        // stage A: [BM][BK] bf16, XOR-swizzled, gathered token rows
#pragma unroll
        for (int c = 0; c < 4; ++c) {
            int row = rb + c * 32;
            const float* src = x + (size_t)tokS[row] * HID + k0 + kbo;
            float4 f0 = *reinterpret_cast<const float4*>(src);
            float4 f1 = *reinterpret_cast<const float4*>(src + 4);
            union { bf16x8 v; short s[8]; } u;
            u.s[0] = f2bf(f0.x); u.s[1] = f2bf(f0.y); u.s[2] = f2bf(f0.z); u.s[3] = f2bf(f0.w);
            u.s[4] = f2bf(f1.x); u.s[5] = f2bf(f1.y); u.s[6] = f2bf(f1.z); u.s[7] = f2bf(f1.w);
            unsigned byte = ((unsigned)(row * (BK * 2) + kbo * 2)) ^ (((unsigned)row & 7u) << 4);
            *reinterpret_cast<bf16x8*>(reinterpret_cast<char*>(As) + byte) = u.v;
        }
        // stage B1/B3: micro-transpose 4x4 into [n][k] bf16, XOR-swizzled
#pragma unroll
        for (int it = 0; it < 2; ++it) {
            int s = tid + it * 256;
            int k = (s >> 5) * 4, n = (s & 31) * 4;
            const float* p1 = W1 + (size_t)(k0 + k) * FFN + gn0 + n;
            const float* p3 = W3 + (size_t)(k0 + k) * FFN + gn0 + n;
            union F4 { float4 v; float f[4]; } r1_[4], r3_[4];
#pragma unroll
            for (int r = 0; r < 4; ++r) {
                r1_[r].v = *reinterpret_cast<const float4*>(p1 + (size_t)r * FFN);
                r3_[r].v = *reinterpret_cast<const float4*>(p3 + (size_t)r * FFN);
            }
#pragma unroll
            for (int c = 0; c < 4; ++c) {
                int nn = n + c;
                bf16x4 v1 = { f2bf(r1_[0].f[c]), f2bf(r1_[1].f[c]), f2bf(r1_[2].f[c]), f2bf(r1_[3].f[c]) };
                bf16x4 v3 = { f2bf(r3_[0].f[c]), f2bf(r3_[1].f[c]), f2bf(r3_[2].f[c]), f2bf(r3_[3].f[c]) };
                unsigned byte = ((unsigned)(nn * (BK * 2) + k * 2)) ^ (((unsigned)nn & 7u) << 4);
                *reinterpret_cast<bf16x4*>(reinterpret_cast<char*>(B1s) + byte) = v1;
                *reinterpret_cast<bf16x4*>(reinterpret_cast<char*>(B3s) + byte) = v3;
            }
        }
        __syncthreads();
#pragma unroll
        for (int ks = 0; ks < 2; ++ks) {
            int kk = ks * 32 + (lane >> 4) * 8;
            bf16x8 af[4], b1f[4], b3f[4];
#pragma unroll
            for (int i = 0; i < 4; ++i) {
                int row = wm + i * 16 + (lane & 15);
                unsigned byte = ((unsigned)(row * (BK * 2) + kk * 2)) ^ (((unsigned)row & 7u) << 4);
                af[i] = *reinterpret_cast<const bf16x8*>(reinterpret_cast<const char*>(As) + byte);
            }
#pragma unroll
            for (int j = 0; j < 4; ++j) {
                int row = wn + j * 16 + (lane & 15);
                unsigned byte = ((unsigned)(row * (BK * 2) + kk * 2)) ^ (((unsigned)row & 7u) << 4);
                b1f[j] = *reinterpret_cast<const bf16x8*>(reinterpret_cast<const char*>(B1s) + byte);
                b3f[j] = *reinterpret_cast<const bf16x8*>(reinterpret_cast<const char*>(B3s) + byte);
            }
#pragma unroll
            for (int i = 0; i < 4; ++i)
#pragma unroll
                for (int j = 0; j < 4; ++j) {
                    acc1[i][j] = __builtin_amdgcn_mfma_f32_16x16x32_bf16(af[i], b1f[j], acc1[i][j], 0, 0, 0);
                    acc3[i][j] = __builtin_amdgcn_mfma_f32_16x16x32_bf16(af[i], b3f[j], acc3[i][j], 0, 0, 0);
                }
        }
        __syncthreads();
    }
    // epilogue: silu(a1)*a3 -> bf16 h
    int hi = lane >> 4, lo = lane & 15;
#pragma unroll
    for (int i = 0; i < 4; ++i) {
#pragma unroll
        for (int q = 0; q < 4; ++q) {
            int rowL = wm + i * 16 + hi * 4 + q;
            if (rowL < rows) {
                __hip_bfloat16* dst = hbuf + (size_t)(base + m0 + rowL) * Fc + n0;
#pragma unroll
                for (int j = 0; j < 4; ++j) {
                    float z = acc1[i][j][q];
                    float hv = (z / (1.f + __expf(-z))) * acc3[i][j][q];
                    dst[wn + j * 16 + lo] = __float2bfloat16(hv);
                }
            }
        }
    }
}

// ---------------- GEMM2: out[tok] += w * (h @ W2), grouped by expert ----------------
__global__ __launch_bounds__(256, 2) void moe_g2(
    const short* __restrict__ hbuf, const float* __restrict__ w2s,
    const int* __restrict__ counts, const int* __restrict__ bases,
    const int* __restrict__ numTiles, const int* __restrict__ tileE, const int* __restrict__ tileM,
    const int* __restrict__ pairTok, const float* __restrict__ pairW,
    float* __restrict__ out, int chunkF0, int Fc)
{
    int ti = blockIdx.y;
    if (ti >= *numTiles) return;
    int e = tileE[ti], m0 = tileM[ti] * BM;
    int base = bases[e], cnt = counts[e];
    int rows = cnt - m0; if (rows > BM) rows = BM;
    int n0 = blockIdx.x * BN;   // over HID

    __shared__ __align__(16) short As[BM * BK];
    __shared__ __align__(16) short Bs[BN * BK];
    __shared__ int tokS[BM];
    __shared__ float wS[BM];

    int tid = threadIdx.x;
    if (tid < BM) {
        tokS[tid] = (tid < rows) ? pairTok[base + m0 + tid] : 0;
        wS[tid]   = (tid < rows) ? pairW[base + m0 + tid] : 0.f;
    }
    __syncthreads();

    int wave = tid >> 6, lane = tid & 63;
    int wm = (wave >> 1) * 64, wn = (wave & 1) * 64;

    f32x4 acc[4][4];
#pragma unroll
    for (int i = 0; i < 4; ++i)
#pragma unroll
        for (int j = 0; j < 4; ++j) acc[i][j] = (f32x4){0.f,0.f,0.f,0.f};

    const float* W2 = w2s + (size_t)e * FFN * HID + (size_t)chunkF0 * HID;
    int rb = tid >> 3, kbo = (tid & 7) * 8;

#pragma unroll 1
    for (int k0 = 0; k0 < Fc; k0 += BK) {
        // stage A: copy bf16 h rows
#pragma unroll
        for (int c = 0; c < 4; ++c) {
            int row = rb + c * 32;
            int pr = (row < rows) ? (base + m0 + row) : base;
            bf16x8 v = *reinterpret_cast<const bf16x8*>(hbuf + (size_t)pr * Fc + k0 + kbo);
            unsigned byte = ((unsigned)(row * (BK * 2) + kbo * 2)) ^ (((unsigned)row & 7u) << 4);
            *reinterpret_cast<bf16x8*>(reinterpret_cast<char*>(As) + byte) = v;
        }
        // stage B: micro-transpose W2 chunk [k][n] -> [n][k]
#pragma unroll
        for (int it = 0; it < 2; ++it) {
            int s = tid + it * 256;
            int k = (s >> 5) * 4, n = (s & 31) * 4;
            const float* p2 = W2 + (size_t)(k0 + k) * HID + n0 + n;
            union F4 { float4 v; float f[4]; } r_[4];
#pragma unroll
            for (int r = 0; r < 4; ++r) r_[r].v = *reinterpret_cast<const float4*>(p2 + (size_t)r * HID);
#pragma unroll
            for (int c = 0; c < 4; ++c) {
                int nn = n + c;
                bf16x4 v = { f2bf(r_[0].f[c]), f2bf(r_[1].f[c]), f2bf(r_[2].f[c]), f2bf(r_[3].f[c]) };
                unsigned byte = ((unsigned)(nn * (BK * 2) + k * 2)) ^ (((unsigned)nn & 7u) << 4);
                *reinterpret_cast<bf16x4*>(reinterpret_cast<char*>(Bs) + byte) = v;
            }
        }
        __syncthreads();
#pragma unroll
        for (int ks = 0; ks < 2; ++ks) {
            int kk = ks * 32 + (lane >> 4) * 8;
            bf16x8 af[4], bf[4];
#pragma unroll
            for (int i = 0; i < 4; ++i) {
                int row = wm + i * 16 + (lane & 15);
                unsigned byte = ((unsigned)(row * (BK * 2) + kk * 2)) ^ (((unsigned)row & 7u) << 4);
                af[i] = *reinterpret_cast<const bf16x8*>(reinterpret_cast<const char*>(As) + byte);
            }
#pragma unroll
            for (int j = 0; j < 4; ++j) {
                int row = wn + j * 16 + (lane & 15);
                unsigned byte = ((unsigned)(row * (BK * 2) + kk * 2)) ^ (((unsigned)row & 7u) << 4);
                bf[j] = *reinterpret_cast<const bf16x8*>(reinterpret_cast<const char*>(Bs) + byte);
            }
#pragma unroll
            for (int i = 0; i < 4; ++i)
#pragma unroll
                for (int j = 0; j < 4; ++j)
                    acc[i][j] = __builtin_amdgcn_mfma_f32_16x16x32_bf16(af[i], bf[j], acc[i][j], 0, 0, 0);
        }
        __syncthreads();
    }
    // epilogue: scaled atomic scatter-add into out
    int hi = lane >> 4, lo = lane & 15;
#pragma unroll
    for (int i = 0; i < 4; ++i) {
#pragma unroll
        for (int q = 0; q < 4; ++q) {
            int rowL = wm + i * 16 + hi * 4 + q;
            if (rowL < rows) {
                float wt = wS[rowL];
                float* dst = out + (size_t)tokS[rowL] * HID + n0;
#pragma unroll
                for (int j = 0; j < 4; ++j)
                    atomicAdd(dst + wn + j * 16 + lo, acc[i][j][q] * wt);
            }
        }
    }
}

// ---------------- host ----------------
extern "C" void kernel_launch(void* const* d_in, const int* in_sizes, int n_in,
                              void* d_out, int out_size, void* d_ws, size_t ws_size,
                              hipStream_t stream)
{
    const float* x   = (const float*)d_in[0];
    const float* gw  = (const float*)d_in[1];
    const float* w1s = (const float*)d_in[2];
    const float* w3s = (const float*)d_in[3];
    const float* w2s = (const float*)d_in[4];
    float* out = (float*)d_out;
    char* ws = (char*)d_ws;

    // ---- workspace layout (fixed: pair arrays hold NPAIR=8192 entries each) ----
    int*   counts   = (int*)(ws + 0);        // 32 B
    int*   numTiles = (int*)(ws + 64);
    int*   bases    = (int*)(ws + 128);      // 32 B
    int*   tileE    = (int*)(ws + 256);      // 288 B
    int*   tileM    = (int*)(ws + 576);      // 288 B
    int*   sel0     = (int*)(ws + 1024);                 // 16 KB
    int*   sel1     = (int*)(ws + 1024 + 4 * T_TOK);     // 16 KB
    float* w0f      = (float*)(ws + 1024 + 8 * T_TOK);   // 16 KB
    float* w1f      = (float*)(ws + 1024 + 12 * T_TOK);  // 16 KB
    int*   pairTok  = (int*)(ws + 1024 + 16 * T_TOK);              // NPAIR*4 = 32 KB
    float* pairW    = (float*)(ws + 1024 + 16 * T_TOK + 4 * NPAIR); // 32 KB
    __hip_bfloat16* hbuf = (__hip_bfloat16*)(ws + 262144);

    // choose FFN chunking so the h intermediate (NPAIR x Fc bf16) fits the workspace
    int NC = 56;
    const int cands[8] = {1, 2, 4, 7, 8, 14, 28, 56};
    for (int i = 0; i < 8; ++i) {
        size_t need = 262144 + (size_t)NPAIR * (FFN / cands[i]) * 2;
        if (need <= ws_size) { NC = cands[i]; break; }
    }
    int Fc = FFN / NC;

    hipMemsetAsync(ws, 0, 1024, stream);
    hipMemsetAsync(d_out, 0, (size_t)out_size * sizeof(float), stream);
    moe_router<<<T_TOK / 4, 256, 0, stream>>>(x, gw, counts, sel0, sel1, w0f, w1f);
    moe_tiles<<<1, 64, 0, stream>>>(counts, bases, tileE, tileM, numTiles);
    moe_scatter<<<NEXP, 256, 0, stream>>>(sel0, sel1, w0f, w1f, bases, pairTok, pairW);
    for (int c = 0; c < NC; ++c) {
        moe_g1<<<dim3(Fc / BN, MAXTILES), 256, 0, stream>>>(
            x, w1s, w3s, counts, bases, numTiles, tileE, tileM, pairTok, hbuf, c * Fc, Fc);
        moe_g2<<<dim3(HID / BN, MAXTILES), 256, 0, stream>>>(
            (const short*)hbuf, w2s, counts, bases, numTiles, tileE, tileM, pairTok, pairW,
            out, c * Fc, Fc);
    }
    (void)in_sizes; (void)n_in;
}